// Round 12
// baseline (168.649 us; speedup 1.0000x reference)
//
#include <hip/hip_runtime.h>
#include <hip/hip_bf16.h>

#define EMB 768
#define NH 8
#define DH 96
#define BATCH 8
#define SEQ 1024
#define M_TOT (BATCH * SEQ)   // 8192 rows of x
#define NCOLS (3 * EMB)       // q(768) | k(768) | v(768) output channels

typedef float f32x4 __attribute__((ext_vector_type(4)));
typedef __bf16 bf16x8 __attribute__((ext_vector_type(8)));

__device__ __forceinline__ unsigned short f2bf_bits(float f) {
  __hip_bfloat16 b = __float2bfloat16(f);
  return *reinterpret_cast<unsigned short*>(&b);
}

__device__ __forceinline__ void gload_lds16(const void* g, void* l) {
  // async global->LDS, 16B per lane; LDS dest is wave-uniform base (+lane*16 by HW)
  __builtin_amdgcn_global_load_lds(
      (__attribute__((address_space(1))) void*)(g),
      (__attribute__((address_space(3))) void*)(l), 16, 0, 0);
}

// ---------------- prep: x fp32 -> bf16 ----------------
__global__ void prep_x_kernel(const float* __restrict__ x, __hip_bfloat16* __restrict__ xb) {
  const int n4 = M_TOT * EMB / 4;
  int i = blockIdx.x * blockDim.x + threadIdx.x;
  if (i < n4) {
    f32x4 v = reinterpret_cast<const f32x4*>(x)[i];
    ushort4 o;
    o.x = f2bf_bits(v[0]);
    o.y = f2bf_bits(v[1]);
    o.z = f2bf_bits(v[2]);
    o.w = f2bf_bits(v[3]);
    reinterpret_cast<ushort4*>(xb)[i] = o;
  }
}

// ---------------- prep: permuted weights -> bf16, bias fp32 ----------------
__global__ void prep_w_kernel(const float* __restrict__ qkv_w, const float* __restrict__ qkv_b,
                              const float* __restrict__ val_w, const float* __restrict__ val_b,
                              __hip_bfloat16* __restrict__ Wall, float* __restrict__ bias) {
  const float inv_s = 0.03608439182435161f;  // 1/sqrt(768)
  int idx = blockIdx.x * 256 + threadIdx.x;
  if (idx >= NCOLS * EMB) return;
  int r = idx / EMB;
  int c = idx - r * EMB;
  float v;
  if (r < EMB) {
    int h = r / DH, d = r - h * DH;
    int src = h * 192 + 2 * d;
    v = qkv_w[(size_t)src * EMB + c] * inv_s;
    if (c == 0) bias[r] = qkv_b[src] * inv_s;
  } else if (r < 2 * EMB) {
    int r2 = r - EMB;
    int h = r2 / DH, d = r2 - h * DH;
    int src = h * 192 + 2 * d + 1;
    v = qkv_w[(size_t)src * EMB + c];
    if (c == 0) bias[r] = qkv_b[src];
  } else {
    int r3 = r - 2 * EMB;
    v = val_w[(size_t)r3 * EMB + c];
    if (c == 0) bias[r] = val_b[r3];
  }
  Wall[idx] = __float2bfloat16(v);
}

// ---------------- fused projection GEMM (m97-structure, 128x128, BK=32) ----------------
// q/k tiles: acc -> LDS (bf16) -> cooperative coalesced store into head-packed
// [b][h][n][96] layout. v tile: direct fp32 NON-TEMPORAL stores (write-once; keep
// L2/L3 for the attn working set that follows).
__global__ __launch_bounds__(256) void gemm_kernel(
    const __hip_bfloat16* __restrict__ xb, const __hip_bfloat16* __restrict__ Wall,
    const float* __restrict__ bias, __hip_bfloat16* __restrict__ qhead,
    __hip_bfloat16* __restrict__ khead, float* __restrict__ vout) {
  __shared__ __hip_bfloat16 As[128 * 32];
  __shared__ __hip_bfloat16 Bs[128 * 32];
  __shared__ __hip_bfloat16 Cs[128][136];  // +8 pad, rows 16B-aligned
  const int tid = threadIdx.x;
  const int w = tid >> 6, l = tid & 63;
  const int m0 = blockIdx.x * 128;
  const int n0 = blockIdx.y * 128;
  const int wr = w >> 1, wc = w & 1;

  f32x4 acc[4][4] = {};

  const int sr0 = (w * 2 + 0) * 16 + (l >> 2);
  const int sr1 = (w * 2 + 1) * 16 + (l >> 2);
  const int sc = (l & 3) * 8;

  for (int kt = 0; kt < EMB / 32; ++kt) {
    const int k0 = kt * 32;
    gload_lds16(xb + (size_t)(m0 + sr0) * EMB + k0 + sc, (void*)(As + (w * 2 + 0) * 512));
    gload_lds16(xb + (size_t)(m0 + sr1) * EMB + k0 + sc, (void*)(As + (w * 2 + 1) * 512));
    gload_lds16(Wall + (size_t)(n0 + sr0) * EMB + k0 + sc, (void*)(Bs + (w * 2 + 0) * 512));
    gload_lds16(Wall + (size_t)(n0 + sr1) * EMB + k0 + sc, (void*)(Bs + (w * 2 + 1) * 512));
    __syncthreads();

    bf16x8 af[4], bfr[4];
#pragma unroll
    for (int t = 0; t < 4; ++t) {
      af[t] = *reinterpret_cast<const bf16x8*>(As + (wr * 64 + t * 16 + (l & 15)) * 32 + (l >> 4) * 8);
      bfr[t] = *reinterpret_cast<const bf16x8*>(Bs + (wc * 64 + t * 16 + (l & 15)) * 32 + (l >> 4) * 8);
    }
#pragma unroll
    for (int i = 0; i < 4; ++i)
#pragma unroll
      for (int j = 0; j < 4; ++j)
        acc[i][j] = __builtin_amdgcn_mfma_f32_16x16x32_bf16(af[i], bfr[j], acc[i][j], 0, 0, 0);
    __syncthreads();
  }

  if (n0 >= 2 * EMB) {
    const int rowbase = m0 + wr * 64;
    const int colbase = n0 - 2 * EMB + wc * 64;
#pragma unroll
    for (int j = 0; j < 4; ++j) {
      const int n = colbase + j * 16 + (l & 15);
      const float bb = bias[2 * EMB + n];
#pragma unroll
      for (int i = 0; i < 4; ++i) {
#pragma unroll
        for (int q = 0; q < 4; ++q) {
          const int m = rowbase + i * 16 + (l >> 4) * 4 + q;
          __builtin_nontemporal_store(acc[i][j][q] + bb, &vout[(size_t)m * EMB + n]);
        }
      }
    }
  } else {
#pragma unroll
    for (int j = 0; j < 4; ++j) {
      const int nl = wc * 64 + j * 16 + (l & 15);
      const float bb = bias[n0 + nl];
#pragma unroll
      for (int i = 0; i < 4; ++i) {
#pragma unroll
        for (int q = 0; q < 4; ++q) {
          const int ml = wr * 64 + i * 16 + (l >> 4) * 4 + q;
          Cs[ml][nl] = __float2bfloat16(acc[i][j][q] + bb);
        }
      }
    }
    __syncthreads();
    __hip_bfloat16* dst = (n0 >= EMB) ? khead : qhead;
    const int ch0 = (n0 >= EMB) ? (n0 - EMB) : n0;
    const int cg = (tid & 15) * 8;
    const int gch = ch0 + cg;
    const int hh = gch / DH, dd = gch - hh * DH;
#pragma unroll
    for (int pass = 0; pass < 8; ++pass) {
      const int r = pass * 16 + (tid >> 4);
      const int m = m0 + r;
      const int bb_ = m >> 10, mm = m & 1023;
      bf16x8 v8 = *reinterpret_cast<const bf16x8*>(&Cs[r][cg]);
      *reinterpret_cast<bf16x8*>(dst + ((size_t)(bb_ * NH + hh) * SEQ + mm) * DH + dd) = v8;
    }
  }
}

// ---------------- fused QK^T + softmax: r11 + LDS score-transpose epilogue ----------------
// Grid 4096 (8 b-variants sharing rel rows co-XCD). 512 thr = 8 waves; block = 16 rows
// x 1024 cols; wave w owns contiguous cols [w*128, +128). K staged per-wave ring-3,
// counted vmcnt (r11, unchanged). NEW: rel loaded ROW-LINEAR (lane <-> 2 rows x 512B,
// 8x128B txns/instr); scores transposed through the DEAD K-ring LDS (row-XOR swizzle
// slot^=(row&7), <=2-way/quarter); softmax in linear domain (5-step shfl_xor per
// 32-lane row group + 2 cross-wave barriers); nt stores row-linear full 128B lines.
// Cuts TA transactions ~26% (rel+store scatter was 16x64B/instr, now 8x128B).
__global__ __launch_bounds__(512, 2) void attn_kernel(
    const __hip_bfloat16* __restrict__ qhead, const __hip_bfloat16* __restrict__ khead,
    const float* __restrict__ rel, float* __restrict__ eout) {
  __shared__ alignas(16) char KS[8 * 3 * 3072];  // 73728 B: K ring; reused as transpose buf
  __shared__ float redm[16][8];
  __shared__ float reds[16][8];

  const int t = threadIdx.x;
  const int w = t >> 6, l = t & 63;
  const int lr = l >> 4, lc = l & 15;  // MFMA-domain coords
  const int rl = l >> 5, cl = l & 31;  // linear-domain coords: row-half, col-group
  // decode: flat = u*64 + b*8 + x ; g = u*8 + x -> b-variants 8 apart = same XCD
  const int flat = blockIdx.x;
  const int u = flat >> 6;
  const int b = (flat >> 3) & 7;
  const int g = u * 8 + (flat & 7);
  const int h = g >> 6;
  const int rb = g & 63;
  const int row0 = rb * 16;
  const size_t bh = (size_t)(b * NH + h);

  // ---- Q fragments direct from head-packed global ----
  const __hip_bfloat16* qsrc = qhead + (bh * SEQ + row0 + lc) * DH;
  bf16x8 qf[3];
#pragma unroll
  for (int kc = 0; kc < 3; ++kc)
    qf[kc] = *reinterpret_cast<const bf16x8*>(qsrc + kc * 32 + lr * 8);

  // ---- rel loads ROW-LINEAR: lane l holds rows (2i+rl), col floats cl*4..+4 ----
  const float* relsrc = rel + ((size_t)h * SEQ + row0 + rl) * SEQ + w * 128 + cl * 4;
  f32x4 relv[8];
#pragma unroll
  for (int i = 0; i < 8; ++i)
    relv[i] = *reinterpret_cast<const f32x4*>(relsrc + (size_t)(2 * i) * SEQ);

  // ---- per-wave K staging: rows [w*128, +128), 16-row chunks of 3KB, ring-3 ----
  const __hip_bfloat16* ksrc = khead + bh * SEQ * DH + (size_t)w * 128 * DH;
  char* kdst = KS + w * 9216;

#define STAGE_K(s, buf)                                                             \
  {                                                                                 \
    const __hip_bfloat16* s_ = ksrc + (size_t)(s) * 1536 + (size_t)l * 8;           \
    gload_lds16(s_, kdst + (buf) * 3072);                                           \
    gload_lds16(s_ + 512, kdst + (buf) * 3072 + 1024);                              \
    gload_lds16(s_ + 1024, kdst + (buf) * 3072 + 2048);                             \
  }

  STAGE_K(0, 0)
  STAGE_K(1, 1)
  __builtin_amdgcn_sched_barrier(0);  // pin q/rel/K01 issue order (vmcnt counts depend on it)

  f32x4 acc[8];
#pragma unroll
  for (int s = 0; s < 8; ++s) {
    if (s < 6) STAGE_K(s + 2, (s + 2) % 3)
    if (s < 6) {
      asm volatile("s_waitcnt vmcnt(6)" ::: "memory");
    } else if (s == 6) {
      asm volatile("s_waitcnt vmcnt(3)" ::: "memory");
    } else {
      asm volatile("s_waitcnt vmcnt(0)" ::: "memory");
    }
    __builtin_amdgcn_sched_barrier(0);
    const __hip_bfloat16* kp =
        reinterpret_cast<const __hip_bfloat16*>(kdst + (s % 3) * 3072) + lc * DH;
    f32x4 a = {0.f, 0.f, 0.f, 0.f};
    __builtin_amdgcn_s_setprio(1);
#pragma unroll
    for (int kc = 0; kc < 3; ++kc) {
      bf16x8 kf = *reinterpret_cast<const bf16x8*>(kp + kc * 32 + lr * 8);
      a = __builtin_amdgcn_mfma_f32_16x16x32_bf16(kf, qf[kc], a, 0, 0, 0);
    }
    __builtin_amdgcn_s_setprio(0);
    acc[s] = a;
  }
#undef STAGE_K
  asm volatile("s_waitcnt lgkmcnt(0)" ::: "memory");  // all kf reads retired: ring is dead
  __builtin_amdgcn_sched_barrier(0);

  // ---- transpose scores through dead K-ring (wave-private, row-XOR swizzle) ----
  // write: (row lc, colbyte s*64+lr*16); read: (row 2i+rl, colbyte cl*16)
#pragma unroll
  for (int s = 0; s < 8; ++s)
    *reinterpret_cast<f32x4*>(kdst + lc * 512 + ((s * 64 + lr * 16) ^ ((lc & 7) << 4))) =
        acc[s];
  asm volatile("s_waitcnt lgkmcnt(0)" ::: "memory");
  __builtin_amdgcn_sched_barrier(0);
  f32x4 v[8];
#pragma unroll
  for (int i = 0; i < 8; ++i) {
    const int r = 2 * i + rl;
    v[i] = *reinterpret_cast<const f32x4*>(kdst + r * 512 + ((cl * 16) ^ ((r & 7) << 4)));
  }

  // ---- add rel in linear domain ----
#pragma unroll
  for (int i = 0; i < 8; ++i) v[i] = v[i] + relv[i];

  // ---- row max: in-lane 4 + shfl over 32-lane row group ----
  float mx[8];
#pragma unroll
  for (int i = 0; i < 8; ++i)
    mx[i] = fmaxf(fmaxf(v[i][0], v[i][1]), fmaxf(v[i][2], v[i][3]));
#pragma unroll
  for (int d = 1; d < 32; d <<= 1)
#pragma unroll
    for (int i = 0; i < 8; ++i) mx[i] = fmaxf(mx[i], __shfl_xor(mx[i], d));
  if (cl == 0) {
#pragma unroll
    for (int i = 0; i < 8; ++i) redm[2 * i + rl][w] = mx[i];
  }
  __syncthreads();
  float M[8];
#pragma unroll
  for (int i = 0; i < 8; ++i) {
    const float* rm = redm[2 * i + rl];
    M[i] = fmaxf(fmaxf(fmaxf(rm[0], rm[1]), fmaxf(rm[2], rm[3])),
                 fmaxf(fmaxf(rm[4], rm[5]), fmaxf(rm[6], rm[7])));
  }

  // ---- exp + row sum ----
  float sm[8];
#pragma unroll
  for (int i = 0; i < 8; ++i) {
    f32x4 e;
    e[0] = __expf(v[i][0] - M[i]);
    e[1] = __expf(v[i][1] - M[i]);
    e[2] = __expf(v[i][2] - M[i]);
    e[3] = __expf(v[i][3] - M[i]);
    v[i] = e;
    sm[i] = (e[0] + e[1]) + (e[2] + e[3]);
  }
#pragma unroll
  for (int d = 1; d < 32; d <<= 1)
#pragma unroll
    for (int i = 0; i < 8; ++i) sm[i] += __shfl_xor(sm[i], d);
  if (cl == 0) {
#pragma unroll
    for (int i = 0; i < 8; ++i) reds[2 * i + rl][w] = sm[i];
  }
  __syncthreads();

  // ---- scale + nt stores, row-linear full lines ----
  float* op = eout + (bh * SEQ + row0 + rl) * SEQ + w * 128 + cl * 4;
#pragma unroll
  for (int i = 0; i < 8; ++i) {
    const float* rs = reds[2 * i + rl];
    const float S = ((rs[0] + rs[1]) + (rs[2] + rs[3])) + ((rs[4] + rs[5]) + (rs[6] + rs[7]));
    f32x4 vv = v[i] * (1.0f / S);
    __builtin_nontemporal_store(vv, reinterpret_cast<f32x4*>(op + (size_t)(2 * i) * SEQ));
  }
}

extern "C" void kernel_launch(void* const* d_in, const int* in_sizes, int n_in,
                              void* d_out, int out_size, void* d_ws, size_t ws_size,
                              hipStream_t stream) {
  const float* x = (const float*)d_in[0];
  const float* rel = (const float*)d_in[1];
  const float* qkv_w = (const float*)d_in[2];
  const float* qkv_b = (const float*)d_in[3];
  const float* val_w = (const float*)d_in[4];
  const float* val_b = (const float*)d_in[5];
  float* out = (float*)d_out;

  char* ws = (char*)d_ws;
  __hip_bfloat16* xb = (__hip_bfloat16*)(ws);                  // 12,582,912
  __hip_bfloat16* Wall = (__hip_bfloat16*)(ws + 12582912);     //  3,538,944
  float* bias = (float*)(ws + 16121856);                       //      9,216
  __hip_bfloat16* qhead = (__hip_bfloat16*)(ws + 16131072);    // 12,582,912  [b][h][n][96]
  __hip_bfloat16* khead = (__hip_bfloat16*)(ws + 28713984);    // 12,582,912  [b][h][n][96]

  float* vout = out;                       // [8192][768] values
  float* eout = out + (size_t)M_TOT * EMB; // [64][1024][1024] energy

  prep_x_kernel<<<dim3(M_TOT * EMB / 4 / 256), dim3(256), 0, stream>>>(x, xb);
  prep_w_kernel<<<dim3(NCOLS * EMB / 256), dim3(256), 0, stream>>>(qkv_w, qkv_b, val_w, val_b,
                                                                   Wall, bias);
  gemm_kernel<<<dim3(M_TOT / 128, NCOLS / 128), dim3(256), 0, stream>>>(xb, Wall, bias, qhead,
                                                                        khead, vout);
  attn_kernel<<<dim3(SEQ / 16 * NH * BATCH), dim3(512), 0, stream>>>(qhead, khead, rel, eout);
}